// Round 2
// baseline (179.621 us; speedup 1.0000x reference)
//
#include <hip/hip_runtime.h>

// Gaussian-kernel regression, fused flash-attention style.
// K_prep: blocks 0..63: yt=y@R^T+t (MFMA bf16) -> yt_perm + yn'
//         blocks 64..191: xn' + X[1:] transposed perm layout
// K_main: fused S^T=yt*Q^T -> exp -> PV (register-direct P), j-split partials
// K_fin : reduce splits (coalesced), divide by rowsum, transpose, store

#define LOG2E 1.44269504088896340736f
#define KNEG (-(1.0f/256.0f)*LOG2E)
#define KA2C (2.0f*(1.0f/256.0f)*LOG2E)

typedef __attribute__((ext_vector_type(4)))  float f32x4;
typedef __attribute__((ext_vector_type(16))) float f32x16;
typedef __attribute__((ext_vector_type(8)))  short bf16x8;
typedef __attribute__((ext_vector_type(4)))  short bf16x4;

#if __has_builtin(__builtin_amdgcn_mfma_f32_32x32x8bf16_1k)
#define PV_DIRECT 1
#else
#define PV_DIRECT 0
#endif

__device__ __forceinline__ unsigned short f2bf(float f) {
  unsigned u = __builtin_bit_cast(unsigned, f);
  u = (u + 0x7fffu + ((u >> 16) & 1u)) >> 16;  // RNE; inputs finite
  return (unsigned short)u;
}
__device__ __forceinline__ unsigned pk2bf(float a, float b) {
  return (unsigned)f2bf(a) | ((unsigned)f2bf(b) << 16);
}
__device__ __forceinline__ bf16x8 pack8(float4 p0, float4 p1) {
  uint4 u;
  u.x = pk2bf(p0.x, p0.y); u.y = pk2bf(p0.z, p0.w);
  u.z = pk2bf(p1.x, p1.y); u.w = pk2bf(p1.z, p1.w);
  return __builtin_bit_cast(bf16x8, u);
}
__device__ __forceinline__ float fast_exp2(float x) {
#if __has_builtin(__builtin_amdgcn_exp2f)
  return __builtin_amdgcn_exp2f(x);
#else
  return exp2f(x);
#endif
}
__device__ __forceinline__ void gl2lds16(const void* g, void* l) {
  __builtin_amdgcn_global_load_lds((const __attribute__((address_space(1))) unsigned int*)g,
                                   (__attribute__((address_space(3))) unsigned int*)l, 16, 0, 0);
}
__device__ __forceinline__ void gl2lds4(const void* g, void* l) {
  __builtin_amdgcn_global_load_lds((const __attribute__((address_space(1))) unsigned int*)g,
                                   (__attribute__((address_space(3))) unsigned int*)l, 4, 0, 0);
}
__device__ __forceinline__ f32x16 mfma_32x32x16(bf16x8 a, bf16x8 b, f32x16 c) {
  return __builtin_amdgcn_mfma_f32_32x32x16_bf16(a, b, c, 0, 0, 0);
}
#if PV_DIRECT
__device__ __forceinline__ f32x16 mfma_32x32x8(bf16x4 a, bf16x4 b, f32x16 c) {
  return __builtin_amdgcn_mfma_f32_32x32x8bf16_1k(a, b, c, 0, 0, 0);
}
#endif

// ---------------- K_prep ----------------
// blocks 0..63  : yt part, 128 rows/block (4 waves x 32 rows)
// blocks 64..191: x part, 64 rows/block
__global__ __launch_bounds__(256) void k_prep(const float* __restrict__ y,
                                              const float* __restrict__ R,
                                              const float* __restrict__ t,
                                              const float* __restrict__ X,
                                              unsigned short* __restrict__ ytp,
                                              float* __restrict__ ynp,
                                              unsigned short* __restrict__ x1tp,
                                              float* __restrict__ xnp) {
  __shared__ union {
    unsigned short ytt[128 * 132];              // yt part: [row-local][c]
    struct { float xt[65 * 132]; float ps[64][4]; } xb;
  } sm;
  const int tid = threadIdx.x;

  if (blockIdx.x < 64) {
    // ------- yt = y@R^T + t -------
    const int wv = tid >> 6, ln = tid & 63;
    const int l = ln & 31, h = ln >> 5;
    const int B = blockIdx.x;
    const int rw = B * 128 + wv * 32;

    bf16x8 af[8];  // A-frag: y[rw+l][kc*16+8h+0..7]
    {
      int row = rw + l; if (row > 8190) row = 8190;
      const float* yr = y + (size_t)row * 128;
#pragma unroll
      for (int kc = 0; kc < 8; ++kc) {
        float4 p0 = *(const float4*)(yr + kc*16 + 8*h);
        float4 p1 = *(const float4*)(yr + kc*16 + 8*h + 4);
        af[kc] = pack8(p0, p1);
      }
    }
    f32x16 acc[4];
#pragma unroll
    for (int cc=0; cc<4; ++cc)
#pragma unroll
      for (int i=0;i<16;++i) acc[cc][i] = 0.f;
#pragma unroll
    for (int cc=0; cc<4; ++cc) {
      const float* Rr = R + (size_t)(cc*32 + l) * 128;  // B-frag: R^T[k][c] = R[c][k]
#pragma unroll
      for (int kc=0; kc<8; ++kc) {
        float4 p0 = *(const float4*)(Rr + kc*16 + 8*h);
        float4 p1 = *(const float4*)(Rr + kc*16 + 8*h + 4);
        acc[cc] = mfma_32x32x16(af[kc], pack8(p0, p1), acc[cc]);
      }
    }
    // D: lane holds yt[rw + (r&3)+8*(r>>2)+4h][cc*32 + l]
    float tv0 = t[l], tv1 = t[32+l], tv2 = t[64+l], tv3 = t[96+l];
    float v0[16], v1[16], v2[16], v3[16], ssq[16];
#pragma unroll
    for (int r=0;r<16;++r) {
      v0[r]=acc[0][r]+tv0; v1[r]=acc[1][r]+tv1; v2[r]=acc[2][r]+tv2; v3[r]=acc[3][r]+tv3;
      ssq[r] = v0[r]*v0[r] + v1[r]*v1[r] + v2[r]*v2[r] + v3[r]*v3[r];
    }
#pragma unroll
    for (int off=1; off<32; off<<=1)
#pragma unroll
      for (int r=0;r<16;++r) ssq[r] += __shfl_xor(ssq[r], off, 64);
    if (l < 16) {
      int r = l;
      int row = rw + (r&3) + 8*(r>>2) + 4*h;
      float val = KNEG * ssq[r];
      if (row >= 8191) val = -1e30f;  // pad j: kills G
      ynp[row] = val;
    }
    // transpose via LDS into perm order
#pragma unroll
    for (int r=0;r<16;++r) {
      int rloc = wv*32 + (r&3) + 8*(r>>2) + 4*h;
      sm.ytt[rloc*132 +   0 + l] = f2bf(v0[r]);
      sm.ytt[rloc*132 +  32 + l] = f2bf(v1[r]);
      sm.ytt[rloc*132 +  64 + l] = f2bf(v2[r]);
      sm.ytt[rloc*132 +  96 + l] = f2bf(v3[r]);
    }
    __syncthreads();
    // perm: [T][jc(2)][kc(8)][lane(64)][8 bf16]; lane ln -> tile-row jc*32+l, k = kc*16+8h
    const int Tt = B*2 + (wv>>1);
    const int jcw = wv & 1;
#pragma unroll
    for (int kc=0;kc<8;++kc) {
      const unsigned short* s = &sm.ytt[(wv*32 + l)*132 + kc*16 + 8*h];
      uint2 a = *(const uint2*)(s);
      uint2 b = *(const uint2*)(s + 4);
      uint4 o; o.x=a.x; o.y=a.y; o.z=b.x; o.w=b.y;
      *(uint4*)(ytp + (size_t)Tt*8192 + jcw*4096 + kc*512 + ln*8) = o;
    }
  } else {
    // ------- xn' + X1^T perm -------
    const int T = blockIdx.x - 64;
    const int jt = T * 64;
    {
      int rr = tid >> 2, q4 = tid & 3;
      int row = jt + rr; if (row > 8191) row = 8191;
      const float* src = X + (size_t)row*128 + q4*32;
      float* dst = &sm.xb.xt[rr*132 + q4*32];
      float s = 0.f;
#pragma unroll
      for (int i=0;i<8;++i) {
        float4 p = *(const float4*)(src + i*4);
        s += p.x*p.x + p.y*p.y + p.z*p.z + p.w*p.w;
        *(float4*)(dst + i*4) = p;
      }
      sm.xb.ps[rr][q4] = s;
      if (tid < 4) {
        int row2 = jt + 64; if (row2 > 8191) row2 = 8191;  // clamp (pad j, G=0)
        const float* s2 = X + (size_t)row2*128 + tid*32;
        float* d2 = &sm.xb.xt[64*132 + tid*32];
#pragma unroll
        for (int i=0;i<8;++i) *(float4*)(d2 + i*4) = *(const float4*)(s2 + i*4);
      }
    }
    __syncthreads();
    if (tid < 64) xnp[jt + tid] = KNEG * (sm.xb.ps[tid][0] + sm.xb.ps[tid][1] +
                                          sm.xb.ps[tid][2] + sm.xb.ps[tid][3]);
#if PV_DIRECT
    // [T][jc(2)][s(4)][cc(4)][lane(64)][4 bf16]: lane -> X1[jc*32+s*8+4h+i][cc*32+l]
#pragma unroll
    for (int it=0; it<8; ++it) {
      int E = tid + it*256;
      int lp = E & 63, grp = E >> 6;
      int cc = grp & 3, s = (grp >> 2) & 3, jc = grp >> 4;
      int jb = jc*32 + s*8 + 4*(lp>>5);
      int c  = cc*32 + (lp & 31);
      uint2 o;
      o.x = pk2bf(sm.xb.xt[(jb+1)*132 + c], sm.xb.xt[(jb+2)*132 + c]);
      o.y = pk2bf(sm.xb.xt[(jb+3)*132 + c], sm.xb.xt[(jb+4)*132 + c]);
      *(uint2*)(x1tp + (size_t)T*8192 + E*4) = o;
    }
#else
    // [T][jc16(4)][cc(4)][lane(64)][8 bf16]: lane -> X1[jc16*16+8h+i][cc*32+l]
#pragma unroll
    for (int it=0; it<4; ++it) {
      int E = tid + it*256;
      int lp = E & 63, grp = E >> 6;
      int cc = grp & 3, jc16 = grp >> 2;
      int jb = jc16*16 + 8*(lp>>5);
      int c  = cc*32 + (lp & 31);
      uint4 o;
      o.x = pk2bf(sm.xb.xt[(jb+1)*132 + c], sm.xb.xt[(jb+2)*132 + c]);
      o.y = pk2bf(sm.xb.xt[(jb+3)*132 + c], sm.xb.xt[(jb+4)*132 + c]);
      o.z = pk2bf(sm.xb.xt[(jb+5)*132 + c], sm.xb.xt[(jb+6)*132 + c]);
      o.w = pk2bf(sm.xb.xt[(jb+7)*132 + c], sm.xb.xt[(jb+8)*132 + c]);
      *(uint4*)(x1tp + (size_t)T*8192 + E*8) = o;
    }
#endif
  }
}

// ---------------- K_main: fused ----------------
// grid (64, JS); block 256 = 4 waves x 32 query rows (BM=128). Each block sweeps tps j-tiles of 64.
__global__ __launch_bounds__(256, 4) void k_main(
    const float* __restrict__ X,
    const unsigned short* __restrict__ ytp,
    const unsigned short* __restrict__ x1tp,
    const float* __restrict__ xnp,
    const float* __restrict__ ynp,
    float* __restrict__ accp,
    float* __restrict__ rsp,
    int tps) {
  __shared__ unsigned short yts[8192];
  __shared__ unsigned short vts[8192];
  __shared__ float yns[64];
#if !PV_DIRECT
  __shared__ unsigned short gls[4*32*68];
#endif
  const int tid = threadIdx.x;
  const int wv = tid >> 6, ln = tid & 63;
  const int l = ln & 31, h = ln >> 5;
  const int row = blockIdx.x*128 + wv*32 + l;  // <= 8191, always valid in X

  bf16x8 qf[8];  // Q as B-operand: Q[row=l][k=kc*16+8h+0..7]
  {
    const float* xr = X + (size_t)row * 128;
#pragma unroll
    for (int kc=0;kc<8;++kc) {
      float4 p0 = *(const float4*)(xr + kc*16 + 8*h);
      float4 p1 = *(const float4*)(xr + kc*16 + 8*h + 4);
      qf[kc] = pack8(p0, p1);
    }
  }
  const float xnl = xnp[row];
  f32x16 acc[4];
#pragma unroll
  for (int cc=0;cc<4;++cc)
#pragma unroll
    for (int i=0;i<16;++i) acc[cc][i]=0.f;
  float rs = 0.f;
  const int T0 = blockIdx.y * tps;
  for (int T = T0; T < T0 + tps; ++T) {
    __syncthreads();  // previous-tile reads done before restage
    {
      const char* yb = (const char*)(ytp + (size_t)T*8192);
      const char* vb = (const char*)(x1tp + (size_t)T*8192);
#pragma unroll
      for (int i=0;i<4;++i) {
        int off = (wv*4 + i) * 1024;
        gl2lds16(yb + off + ln*16, (char*)yts + off);
        gl2lds16(vb + off + ln*16, (char*)vts + off);
      }
      if (wv == 0) gl2lds4(ynp + T*64 + ln, (char*)yns);
    }
    __syncthreads();  // drains vmcnt -> staged data visible
#pragma unroll
    for (int jc=0; jc<2; ++jc) {
      f32x16 sa;
#pragma unroll
      for (int i=0;i<16;++i) sa[i]=0.f;
#pragma unroll
      for (int kc=0;kc<8;++kc) {  // S^T = yt * Q^T
        bf16x8 a = *(const bf16x8*)((const char*)yts + (jc*8+kc)*1024 + ln*16);
        sa = mfma_32x32x16(a, qf[kc], sa);
      }
      // lane holds S^T[j = jc*32+(r&3)+8(r>>2)+4h][m = l]
      float gg[16];
#pragma unroll
      for (int rg=0; rg<4; ++rg) {
        f32x4 yv = *(const f32x4*)((const char*)yns + (jc*32 + rg*8 + 4*h)*4);
#pragma unroll
        for (int i=0;i<4;++i) {
          float e = fmaf(sa[rg*4+i], KA2C, xnl + yv[i]);
          e = fminf(e, 0.f);          // clip(sq,0)
          float g = fast_exp2(e);
          gg[rg*4+i] = g;
          rs += g;
        }
      }
#if PV_DIRECT
      bf16x4 pf[4];  // slab s: regs 4s..4s+3 are exactly B-op of 32x32x8 (k=4h+i)
#pragma unroll
      for (int s=0;s<4;++s) {
        uint2 u;
        u.x = pk2bf(gg[4*s+0], gg[4*s+1]);
        u.y = pk2bf(gg[4*s+2], gg[4*s+3]);
        pf[s] = __builtin_bit_cast(bf16x4, u);
      }
#pragma unroll
      for (int s=0;s<4;++s)
#pragma unroll
        for (int cc=0;cc<4;++cc) {
          bf16x4 a = *(const bf16x4*)((const char*)vts + ((jc*16 + s*4 + cc)*512) + ln*8);
          acc[cc] = mfma_32x32x8(a, pf[s], acc[cc]);  // acc^T += V^T * P^T
        }
#else
#pragma unroll
      for (int p=0;p<8;++p) {
        int j0 = jc*32 + 2*(p&1) + 8*(p>>1) + 4*h;
        *(unsigned*)&gls[(wv*32 + l)*68 + j0] = pk2bf(gg[2*p], gg[2*p+1]);
      }
      __builtin_amdgcn_wave_barrier();  // cross-lane LDS visibility within wave
#pragma unroll
      for (int jj=0; jj<2; ++jj) {
        int jc16 = jc*2 + jj;
        const unsigned short* gp = &gls[(wv*32 + l)*68 + jc16*16 + 8*h];
        uint2 g0 = *(const uint2*)(gp);
        uint2 g1 = *(const uint2*)(gp + 4);
        uint4 gv; gv.x=g0.x; gv.y=g0.y; gv.z=g1.x; gv.w=g1.y;
        bf16x8 pb = __builtin_bit_cast(bf16x8, gv);
#pragma unroll
        for (int cc=0;cc<4;++cc) {
          bf16x8 a2 = *(const bf16x8*)((const char*)vts + (jc16*4+cc)*1024 + ln*16);
          acc[cc] = mfma_32x32x16(a2, pb, acc[cc]);
        }
      }
      __builtin_amdgcn_wave_barrier();
#endif
    }
  }
  rs += __shfl_xor(rs, 32, 64);
  const int sp = blockIdx.y;
  if (h == 0) rsp[(size_t)sp*8192 + row] = rs;
  // acc^T: lane holds out^T[c = cc*32+(r&3)+8(r>>2)+4h][m = row]; store [sp][c][row]
#pragma unroll
  for (int cc=0;cc<4;++cc)
#pragma unroll
    for (int r=0;r<16;++r) {
      int c = cc*32 + (r&3) + 8*(r>>2) + 4*h;
      accp[((size_t)sp*128 + c)*8192 + row] = acc[cc][r];
    }
}

// ---------------- K_fin: coalesced split-reduce + normalize + transpose ----------------
// grid 128 x 256. Block: 64 rows x 128 cols. Thread: rows rq*4..+3 (r-contig float4), cols cg*8..+7.
__global__ __launch_bounds__(256) void k_fin(const float* __restrict__ accp,
                                             const float* __restrict__ rsp,
                                             float* __restrict__ out,
                                             int js) {
  __shared__ float tr[64*132];
  __shared__ float rinv[64];
  const int tid = threadIdx.x;
  const int r0 = blockIdx.x * 64;
  if (tid < 64) {
    float s = 0.f;
    for (int sp=0; sp<js; ++sp) s += rsp[(size_t)sp*8192 + r0 + tid];
    rinv[tid] = 1.f / s;
  }
  const int rq = tid & 15, cg = tid >> 4;
  float v[8][4];
#pragma unroll
  for (int cc=0;cc<8;++cc)
#pragma unroll
    for (int k=0;k<4;++k) v[cc][k]=0.f;
  for (int sp=0; sp<js; ++sp) {
    const float* base = accp + ((size_t)sp*128 + cg*8)*8192 + r0 + rq*4;
#pragma unroll
    for (int cc=0; cc<8; ++cc) {
      float4 p = *(const float4*)(base + (size_t)cc*8192);
      v[cc][0]+=p.x; v[cc][1]+=p.y; v[cc][2]+=p.z; v[cc][3]+=p.w;
    }
  }
  __syncthreads();
#pragma unroll
  for (int cc=0;cc<8;++cc)
#pragma unroll
    for (int k=0;k<4;++k)
      tr[(rq*4+k)*132 + cg*8+cc] = v[cc][k] * rinv[rq*4+k];
  __syncthreads();
  {
    int r = tid >> 2, q = tid & 3;
    int grow = r0 + r;
    if (grow < 8191) {
      float* dst = out + (size_t)grow*128 + q*32;
      const float* s2 = &tr[r*132 + q*32];
#pragma unroll
      for (int i=0;i<8;++i) *(float4*)(dst + i*4) = *(const float4*)(s2 + i*4);
    }
  }
}

extern "C" void kernel_launch(void* const* d_in, const int* in_sizes, int n_in,
                              void* d_out, int out_size, void* d_ws, size_t ws_size,
                              hipStream_t stream) {
  const float* X = (const float*)d_in[0];
  const float* y = (const float*)d_in[1];
  // d_in[2] = y_next (unused by reference)
  const float* R = (const float*)d_in[3];
  const float* t = (const float*)d_in[4];
  float* out = (float*)d_out;
  char* ws = (char*)d_ws;

  unsigned short* ytp  = (unsigned short*)(ws);                              // 2 MB
  unsigned short* x1tp = (unsigned short*)(ws + (size_t)8192*128*2);         // 2 MB
  float* ynp = (float*)(ws + (size_t)4*1024*1024);                           // 32 KB
  float* xnp = (float*)(ws + (size_t)4*1024*1024 + 32*1024);                 // 32 KB
  float* rsp = (float*)(ws + (size_t)4*1024*1024 + 64*1024);                 // <=512 KB
  size_t accoff = (size_t)4*1024*1024 + 64*1024 + 512*1024;
  float* accp = (float*)(ws + accoff);

  int js = 16;  // j-split factor -> 4 blocks/CU; shrink if workspace small
  while (js > 1 && accoff + (size_t)js*128*8192*4 > ws_size) js >>= 1;
  int tps = 128 / js;

  k_prep<<<dim3(192), dim3(256), 0, stream>>>(y, R, t, X, ytp, ynp, x1tp, xnp);
  k_main<<<dim3(64, js), dim3(256), 0, stream>>>(X, ytp, x1tp, xnp, ynp, accp, rsp, tps);
  k_fin<<<dim3(128), dim3(256), 0, stream>>>(accp, rsp, out, js);
}

// Round 3
// 144.735 us; speedup vs baseline: 1.2410x; 1.2410x over previous
//
#include <hip/hip_runtime.h>

// Gaussian-kernel regression, fused flash-attention style.
// K_prep: blocks 0..63: yt=y@R^T+t (MFMA bf16) -> yt_perm + yn'
//         blocks 64..191: xn' + X[1:] transposed perm layout
// K_main: fused S^T=yt*Q^T -> exp -> PV (register-direct P), j-split partials
//         grid 64 x js=12 = 768 blocks = exactly 3/CU (reg capacity 512/164),
//         __launch_bounds__(256,3): cap 170 regs -> NO SPILL (256,4 spilled: R2)
// K_fin : reduce splits (coalesced), divide by rowsum, transpose, store

#define LOG2E 1.44269504088896340736f
#define KNEG (-(1.0f/256.0f)*LOG2E)
#define KA2C (2.0f*(1.0f/256.0f)*LOG2E)

typedef __attribute__((ext_vector_type(4)))  float f32x4;
typedef __attribute__((ext_vector_type(16))) float f32x16;
typedef __attribute__((ext_vector_type(8)))  short bf16x8;
typedef __attribute__((ext_vector_type(4)))  short bf16x4;

#if __has_builtin(__builtin_amdgcn_mfma_f32_32x32x8bf16_1k)
#define PV_DIRECT 1
#else
#define PV_DIRECT 0
#endif

__device__ __forceinline__ unsigned short f2bf(float f) {
  unsigned u = __builtin_bit_cast(unsigned, f);
  u = (u + 0x7fffu + ((u >> 16) & 1u)) >> 16;  // RNE; inputs finite
  return (unsigned short)u;
}
__device__ __forceinline__ unsigned pk2bf(float a, float b) {
  return (unsigned)f2bf(a) | ((unsigned)f2bf(b) << 16);
}
__device__ __forceinline__ bf16x8 pack8(float4 p0, float4 p1) {
  uint4 u;
  u.x = pk2bf(p0.x, p0.y); u.y = pk2bf(p0.z, p0.w);
  u.z = pk2bf(p1.x, p1.y); u.w = pk2bf(p1.z, p1.w);
  return __builtin_bit_cast(bf16x8, u);
}
__device__ __forceinline__ float fast_exp2(float x) {
#if __has_builtin(__builtin_amdgcn_exp2f)
  return __builtin_amdgcn_exp2f(x);
#else
  return exp2f(x);
#endif
}
__device__ __forceinline__ void gl2lds16(const void* g, void* l) {
  __builtin_amdgcn_global_load_lds((const __attribute__((address_space(1))) unsigned int*)g,
                                   (__attribute__((address_space(3))) unsigned int*)l, 16, 0, 0);
}
__device__ __forceinline__ void gl2lds4(const void* g, void* l) {
  __builtin_amdgcn_global_load_lds((const __attribute__((address_space(1))) unsigned int*)g,
                                   (__attribute__((address_space(3))) unsigned int*)l, 4, 0, 0);
}
__device__ __forceinline__ f32x16 mfma_32x32x16(bf16x8 a, bf16x8 b, f32x16 c) {
  return __builtin_amdgcn_mfma_f32_32x32x16_bf16(a, b, c, 0, 0, 0);
}
#if PV_DIRECT
__device__ __forceinline__ f32x16 mfma_32x32x8(bf16x4 a, bf16x4 b, f32x16 c) {
  return __builtin_amdgcn_mfma_f32_32x32x8bf16_1k(a, b, c, 0, 0, 0);
}
#endif

// ---------------- K_prep ----------------
// blocks 0..63  : yt part, 128 rows/block (4 waves x 32 rows)
// blocks 64..191: x part, 64 rows/block
__global__ __launch_bounds__(256) void k_prep(const float* __restrict__ y,
                                              const float* __restrict__ R,
                                              const float* __restrict__ t,
                                              const float* __restrict__ X,
                                              unsigned short* __restrict__ ytp,
                                              float* __restrict__ ynp,
                                              unsigned short* __restrict__ x1tp,
                                              float* __restrict__ xnp) {
  __shared__ union {
    unsigned short ytt[128 * 132];              // yt part: [row-local][c]
    struct { float xt[65 * 132]; float ps[64][4]; } xb;
  } sm;
  const int tid = threadIdx.x;

  if (blockIdx.x < 64) {
    // ------- yt = y@R^T + t -------
    const int wv = tid >> 6, ln = tid & 63;
    const int l = ln & 31, h = ln >> 5;
    const int B = blockIdx.x;
    const int rw = B * 128 + wv * 32;

    bf16x8 af[8];  // A-frag: y[rw+l][kc*16+8h+0..7]
    {
      int row = rw + l; if (row > 8190) row = 8190;
      const float* yr = y + (size_t)row * 128;
#pragma unroll
      for (int kc = 0; kc < 8; ++kc) {
        float4 p0 = *(const float4*)(yr + kc*16 + 8*h);
        float4 p1 = *(const float4*)(yr + kc*16 + 8*h + 4);
        af[kc] = pack8(p0, p1);
      }
    }
    f32x16 acc[4];
#pragma unroll
    for (int cc=0; cc<4; ++cc)
#pragma unroll
      for (int i=0;i<16;++i) acc[cc][i] = 0.f;
#pragma unroll
    for (int cc=0; cc<4; ++cc) {
      const float* Rr = R + (size_t)(cc*32 + l) * 128;  // B-frag: R^T[k][c] = R[c][k]
#pragma unroll
      for (int kc=0; kc<8; ++kc) {
        float4 p0 = *(const float4*)(Rr + kc*16 + 8*h);
        float4 p1 = *(const float4*)(Rr + kc*16 + 8*h + 4);
        acc[cc] = mfma_32x32x16(af[kc], pack8(p0, p1), acc[cc]);
      }
    }
    // D: lane holds yt[rw + (r&3)+8*(r>>2)+4h][cc*32 + l]
    float tv0 = t[l], tv1 = t[32+l], tv2 = t[64+l], tv3 = t[96+l];
    float v0[16], v1[16], v2[16], v3[16], ssq[16];
#pragma unroll
    for (int r=0;r<16;++r) {
      v0[r]=acc[0][r]+tv0; v1[r]=acc[1][r]+tv1; v2[r]=acc[2][r]+tv2; v3[r]=acc[3][r]+tv3;
      ssq[r] = v0[r]*v0[r] + v1[r]*v1[r] + v2[r]*v2[r] + v3[r]*v3[r];
    }
#pragma unroll
    for (int off=1; off<32; off<<=1)
#pragma unroll
      for (int r=0;r<16;++r) ssq[r] += __shfl_xor(ssq[r], off, 64);
    if (l < 16) {
      int r = l;
      int row = rw + (r&3) + 8*(r>>2) + 4*h;
      float val = KNEG * ssq[r];
      if (row >= 8191) val = -1e30f;  // pad j: kills G
      ynp[row] = val;
    }
    // transpose via LDS into perm order
#pragma unroll
    for (int r=0;r<16;++r) {
      int rloc = wv*32 + (r&3) + 8*(r>>2) + 4*h;
      sm.ytt[rloc*132 +   0 + l] = f2bf(v0[r]);
      sm.ytt[rloc*132 +  32 + l] = f2bf(v1[r]);
      sm.ytt[rloc*132 +  64 + l] = f2bf(v2[r]);
      sm.ytt[rloc*132 +  96 + l] = f2bf(v3[r]);
    }
    __syncthreads();
    // perm: [T][jc(2)][kc(8)][lane(64)][8 bf16]; lane ln -> tile-row jc*32+l, k = kc*16+8h
    const int Tt = B*2 + (wv>>1);
    const int jcw = wv & 1;
#pragma unroll
    for (int kc=0;kc<8;++kc) {
      const unsigned short* s = &sm.ytt[(wv*32 + l)*132 + kc*16 + 8*h];
      uint2 a = *(const uint2*)(s);
      uint2 b = *(const uint2*)(s + 4);
      uint4 o; o.x=a.x; o.y=a.y; o.z=b.x; o.w=b.y;
      *(uint4*)(ytp + (size_t)Tt*8192 + jcw*4096 + kc*512 + ln*8) = o;
    }
  } else {
    // ------- xn' + X1^T perm -------
    const int T = blockIdx.x - 64;
    const int jt = T * 64;
    {
      int rr = tid >> 2, q4 = tid & 3;
      int row = jt + rr; if (row > 8191) row = 8191;
      const float* src = X + (size_t)row*128 + q4*32;
      float* dst = &sm.xb.xt[rr*132 + q4*32];
      float s = 0.f;
#pragma unroll
      for (int i=0;i<8;++i) {
        float4 p = *(const float4*)(src + i*4);
        s += p.x*p.x + p.y*p.y + p.z*p.z + p.w*p.w;
        *(float4*)(dst + i*4) = p;
      }
      sm.xb.ps[rr][q4] = s;
      if (tid < 4) {
        int row2 = jt + 64; if (row2 > 8191) row2 = 8191;  // clamp (pad j, G=0)
        const float* s2 = X + (size_t)row2*128 + tid*32;
        float* d2 = &sm.xb.xt[64*132 + tid*32];
#pragma unroll
        for (int i=0;i<8;++i) *(float4*)(d2 + i*4) = *(const float4*)(s2 + i*4);
      }
    }
    __syncthreads();
    if (tid < 64) xnp[jt + tid] = KNEG * (sm.xb.ps[tid][0] + sm.xb.ps[tid][1] +
                                          sm.xb.ps[tid][2] + sm.xb.ps[tid][3]);
#if PV_DIRECT
    // [T][jc(2)][s(4)][cc(4)][lane(64)][4 bf16]: lane -> X1[jc*32+s*8+4h+i][cc*32+l]
#pragma unroll
    for (int it=0; it<8; ++it) {
      int E = tid + it*256;
      int lp = E & 63, grp = E >> 6;
      int cc = grp & 3, s = (grp >> 2) & 3, jc = grp >> 4;
      int jb = jc*32 + s*8 + 4*(lp>>5);
      int c  = cc*32 + (lp & 31);
      uint2 o;
      o.x = pk2bf(sm.xb.xt[(jb+1)*132 + c], sm.xb.xt[(jb+2)*132 + c]);
      o.y = pk2bf(sm.xb.xt[(jb+3)*132 + c], sm.xb.xt[(jb+4)*132 + c]);
      *(uint2*)(x1tp + (size_t)T*8192 + E*4) = o;
    }
#else
    // [T][jc16(4)][cc(4)][lane(64)][8 bf16]: lane -> X1[jc16*16+8h+i][cc*32+l]
#pragma unroll
    for (int it=0; it<4; ++it) {
      int E = tid + it*256;
      int lp = E & 63, grp = E >> 6;
      int cc = grp & 3, jc16 = grp >> 2;
      int jb = jc16*16 + 8*(lp>>5);
      int c  = cc*32 + (lp & 31);
      uint4 o;
      o.x = pk2bf(sm.xb.xt[(jb+1)*132 + c], sm.xb.xt[(jb+2)*132 + c]);
      o.y = pk2bf(sm.xb.xt[(jb+3)*132 + c], sm.xb.xt[(jb+4)*132 + c]);
      o.z = pk2bf(sm.xb.xt[(jb+5)*132 + c], sm.xb.xt[(jb+6)*132 + c]);
      o.w = pk2bf(sm.xb.xt[(jb+7)*132 + c], sm.xb.xt[(jb+8)*132 + c]);
      *(uint4*)(x1tp + (size_t)T*8192 + E*8) = o;
    }
#endif
  }
}

// ---------------- K_main: fused ----------------
// grid (64, js); block 256 = 4 waves x 32 query rows (BM=128).
// Block sweeps j-tiles [sp*128/js, (sp+1)*128/js).
__global__ __launch_bounds__(256, 3) void k_main(
    const float* __restrict__ X,
    const unsigned short* __restrict__ ytp,
    const unsigned short* __restrict__ x1tp,
    const float* __restrict__ xnp,
    const float* __restrict__ ynp,
    float* __restrict__ accp,
    float* __restrict__ rsp,
    int js) {
  __shared__ unsigned short yts[8192];
  __shared__ unsigned short vts[8192];
  __shared__ float yns[64];
#if !PV_DIRECT
  __shared__ unsigned short gls[4*32*68];
#endif
  const int tid = threadIdx.x;
  const int wv = tid >> 6, ln = tid & 63;
  const int l = ln & 31, h = ln >> 5;
  const int row = blockIdx.x*128 + wv*32 + l;  // <= 8191, always valid in X

  bf16x8 qf[8];  // Q as B-operand: Q[row=l][k=kc*16+8h+0..7]
  {
    const float* xr = X + (size_t)row * 128;
#pragma unroll
    for (int kc=0;kc<8;++kc) {
      float4 p0 = *(const float4*)(xr + kc*16 + 8*h);
      float4 p1 = *(const float4*)(xr + kc*16 + 8*h + 4);
      qf[kc] = pack8(p0, p1);
    }
  }
  const float xnl = xnp[row];
  f32x16 acc[4];
#pragma unroll
  for (int cc=0;cc<4;++cc)
#pragma unroll
    for (int i=0;i<16;++i) acc[cc][i]=0.f;
  float rs = 0.f;
  const int sp = blockIdx.y;
  const int Tbeg = (sp * 128) / js;
  const int Tend = ((sp + 1) * 128) / js;
  for (int T = Tbeg; T < Tend; ++T) {
    __syncthreads();  // previous-tile reads done before restage
    {
      const char* yb = (const char*)(ytp + (size_t)T*8192);
      const char* vb = (const char*)(x1tp + (size_t)T*8192);
#pragma unroll
      for (int i=0;i<4;++i) {
        int off = (wv*4 + i) * 1024;
        gl2lds16(yb + off + ln*16, (char*)yts + off);
        gl2lds16(vb + off + ln*16, (char*)vts + off);
      }
      if (wv == 0) gl2lds4(ynp + T*64 + ln, (char*)yns);
    }
    __syncthreads();  // drains vmcnt -> staged data visible
#pragma unroll
    for (int jc=0; jc<2; ++jc) {
      f32x16 sa;
#pragma unroll
      for (int i=0;i<16;++i) sa[i]=0.f;
#pragma unroll
      for (int kc=0;kc<8;++kc) {  // S^T = yt * Q^T
        bf16x8 a = *(const bf16x8*)((const char*)yts + (jc*8+kc)*1024 + ln*16);
        sa = mfma_32x32x16(a, qf[kc], sa);
      }
      // lane holds S^T[j = jc*32+(r&3)+8(r>>2)+4h][m = l]
      float gg[16];
#pragma unroll
      for (int rg=0; rg<4; ++rg) {
        f32x4 yv = *(const f32x4*)((const char*)yns + (jc*32 + rg*8 + 4*h)*4);
#pragma unroll
        for (int i=0;i<4;++i) {
          float e = fmaf(sa[rg*4+i], KA2C, xnl + yv[i]);
          e = fminf(e, 0.f);          // clip(sq,0)
          float g = fast_exp2(e);
          gg[rg*4+i] = g;
          rs += g;
        }
      }
#if PV_DIRECT
      bf16x4 pf[4];  // slab s: regs 4s..4s+3 are exactly B-op of 32x32x8 (k=4h+i)
#pragma unroll
      for (int s=0;s<4;++s) {
        uint2 u;
        u.x = pk2bf(gg[4*s+0], gg[4*s+1]);
        u.y = pk2bf(gg[4*s+2], gg[4*s+3]);
        pf[s] = __builtin_bit_cast(bf16x4, u);
      }
#pragma unroll
      for (int s=0;s<4;++s)
#pragma unroll
        for (int cc=0;cc<4;++cc) {
          bf16x4 a = *(const bf16x4*)((const char*)vts + ((jc*16 + s*4 + cc)*512) + ln*8);
          acc[cc] = mfma_32x32x8(a, pf[s], acc[cc]);  // acc^T += V^T * P^T
        }
#else
#pragma unroll
      for (int p=0;p<8;++p) {
        int j0 = jc*32 + 2*(p&1) + 8*(p>>1) + 4*h;
        *(unsigned*)&gls[(wv*32 + l)*68 + j0] = pk2bf(gg[2*p], gg[2*p+1]);
      }
      __builtin_amdgcn_wave_barrier();  // cross-lane LDS visibility within wave
#pragma unroll
      for (int jj=0; jj<2; ++jj) {
        int jc16 = jc*2 + jj;
        const unsigned short* gp = &gls[(wv*32 + l)*68 + jc16*16 + 8*h];
        uint2 g0 = *(const uint2*)(gp);
        uint2 g1 = *(const uint2*)(gp + 4);
        uint4 gv; gv.x=g0.x; gv.y=g0.y; gv.z=g1.x; gv.w=g1.y;
        bf16x8 pb = __builtin_bit_cast(bf16x8, gv);
#pragma unroll
        for (int cc=0;cc<4;++cc) {
          bf16x8 a2 = *(const bf16x8*)((const char*)vts + (jc16*4+cc)*1024 + ln*16);
          acc[cc] = mfma_32x32x16(a2, pb, acc[cc]);
        }
      }
      __builtin_amdgcn_wave_barrier();
#endif
    }
  }
  rs += __shfl_xor(rs, 32, 64);
  if (h == 0) rsp[(size_t)sp*8192 + row] = rs;
  // acc^T: lane holds out^T[c = cc*32+(r&3)+8(r>>2)+4h][m = row]; store [sp][c][row]
#pragma unroll
  for (int cc=0;cc<4;++cc)
#pragma unroll
    for (int r=0;r<16;++r) {
      int c = cc*32 + (r&3) + 8*(r>>2) + 4*h;
      accp[((size_t)sp*128 + c)*8192 + row] = acc[cc][r];
    }
}

// ---------------- K_fin: coalesced split-reduce + normalize + transpose ----------------
// grid 128 x 256. Block: 64 rows x 128 cols. Thread: rows rq*4..+3 (r-contig float4), cols cg*8..+7.
__global__ __launch_bounds__(256) void k_fin(const float* __restrict__ accp,
                                             const float* __restrict__ rsp,
                                             float* __restrict__ out,
                                             int js) {
  __shared__ float tr[64*132];
  __shared__ float rinv[64];
  const int tid = threadIdx.x;
  const int r0 = blockIdx.x * 64;
  if (tid < 64) {
    float s = 0.f;
    for (int sp=0; sp<js; ++sp) s += rsp[(size_t)sp*8192 + r0 + tid];
    rinv[tid] = 1.f / s;
  }
  const int rq = tid & 15, cg = tid >> 4;
  float v[8][4];
#pragma unroll
  for (int cc=0;cc<8;++cc)
#pragma unroll
    for (int k=0;k<4;++k) v[cc][k]=0.f;
  for (int sp=0; sp<js; ++sp) {
    const float* base = accp + ((size_t)sp*128 + cg*8)*8192 + r0 + rq*4;
#pragma unroll
    for (int cc=0; cc<8; ++cc) {
      float4 p = *(const float4*)(base + (size_t)cc*8192);
      v[cc][0]+=p.x; v[cc][1]+=p.y; v[cc][2]+=p.z; v[cc][3]+=p.w;
    }
  }
  __syncthreads();
#pragma unroll
  for (int cc=0;cc<8;++cc)
#pragma unroll
    for (int k=0;k<4;++k)
      tr[(rq*4+k)*132 + cg*8+cc] = v[cc][k] * rinv[rq*4+k];
  __syncthreads();
  {
    int r = tid >> 2, q = tid & 3;
    int grow = r0 + r;
    if (grow < 8191) {
      float* dst = out + (size_t)grow*128 + q*32;
      const float* s2 = &tr[r*132 + q*32];
#pragma unroll
      for (int i=0;i<8;++i) *(float4*)(dst + i*4) = *(const float4*)(s2 + i*4);
    }
  }
}

extern "C" void kernel_launch(void* const* d_in, const int* in_sizes, int n_in,
                              void* d_out, int out_size, void* d_ws, size_t ws_size,
                              hipStream_t stream) {
  const float* X = (const float*)d_in[0];
  const float* y = (const float*)d_in[1];
  // d_in[2] = y_next (unused by reference)
  const float* R = (const float*)d_in[3];
  const float* t = (const float*)d_in[4];
  float* out = (float*)d_out;
  char* ws = (char*)d_ws;

  unsigned short* ytp  = (unsigned short*)(ws);                              // 2 MB
  unsigned short* x1tp = (unsigned short*)(ws + (size_t)8192*128*2);         // 2 MB
  float* ynp = (float*)(ws + (size_t)4*1024*1024);                           // 32 KB
  float* xnp = (float*)(ws + (size_t)4*1024*1024 + 32*1024);                 // 32 KB
  float* rsp = (float*)(ws + (size_t)4*1024*1024 + 64*1024);                 // <=512 KB
  size_t accoff = (size_t)4*1024*1024 + 64*1024 + 512*1024;
  float* accp = (float*)(ws + accoff);

  int js = 12;  // 64 x 12 = 768 blocks = exactly 3 blocks/CU (reg-capacity limit)
  while (js > 1 && accoff + (size_t)js*128*8192*4 > ws_size) js >>= 1;

  k_prep<<<dim3(192), dim3(256), 0, stream>>>(y, R, t, X, ytp, ynp, x1tp, xnp);
  k_main<<<dim3(64, js), dim3(256), 0, stream>>>(X, ytp, x1tp, xnp, ynp, accp, rsp, js);
  k_fin<<<dim3(128), dim3(256), 0, stream>>>(accp, rsp, out, js);
}

// Round 5
// 140.293 us; speedup vs baseline: 1.2803x; 1.0317x over previous
//
#include <hip/hip_runtime.h>
#include <hip/hip_bf16.h>

// Gaussian-kernel regression, fused flash-attention style.
// Exponent folded into MFMA: K=144, A=[KA2C*yt, yn_hi, yn_lo, 0...], B=[x, 1, 1, 0...]
//   (xn row-constant -> cancels in G/rowsum; clamp inactive in exact math)
// PV at full rate 32x32x16 via per-wave LDS P round-trip.
// K_prep: blocks 0..63: yt GEMM -> scaled perm + yn slots; 64..191: V perm
// K_main: S=exp-arg via 9 MFMAs -> exp2 -> LDS -> PV, j-split partials
// K_fin : reduce splits, normalize, transpose, store

#define LOG2E 1.44269504088896340736f
#define KNEG (-(1.0f/256.0f)*LOG2E)
#define KA2C (2.0f*(1.0f/256.0f)*LOG2E)

typedef __attribute__((ext_vector_type(4)))  float f32x4;
typedef __attribute__((ext_vector_type(16))) float f32x16;
typedef __attribute__((ext_vector_type(8)))  short bf16x8;

__device__ __forceinline__ unsigned short f2bf(float f) {
  unsigned u = __builtin_bit_cast(unsigned, f);
  u = (u + 0x7fffu + ((u >> 16) & 1u)) >> 16;  // RNE; inputs finite
  return (unsigned short)u;
}
__device__ __forceinline__ unsigned pk2bf(float a, float b) {
  __hip_bfloat162 h = __float22bfloat162_rn(float2{a, b});  // v_cvt_pk_bf16_f32 on gfx950
  unsigned u;
  __builtin_memcpy(&u, &h, 4);   // bit_cast rejected: __hip_bfloat162 non-trivial
  return u;
}
__device__ __forceinline__ bf16x8 pack8(float4 p0, float4 p1) {
  uint4 u;
  u.x = pk2bf(p0.x, p0.y); u.y = pk2bf(p0.z, p0.w);
  u.z = pk2bf(p1.x, p1.y); u.w = pk2bf(p1.z, p1.w);
  return __builtin_bit_cast(bf16x8, u);
}
__device__ __forceinline__ float fast_exp2(float x) {
#if __has_builtin(__builtin_amdgcn_exp2f)
  return __builtin_amdgcn_exp2f(x);
#else
  return exp2f(x);
#endif
}
__device__ __forceinline__ void gl2lds16(const void* g, void* l) {
  __builtin_amdgcn_global_load_lds((const __attribute__((address_space(1))) unsigned int*)g,
                                   (__attribute__((address_space(3))) unsigned int*)l, 16, 0, 0);
}
__device__ __forceinline__ f32x16 mfma_32x32x16(bf16x8 a, bf16x8 b, f32x16 c) {
  return __builtin_amdgcn_mfma_f32_32x32x16_bf16(a, b, c, 0, 0, 0);
}

#define T_STRIDE 34816   // per-tile bytes: 2 jc x 9 kc x 1024 (yt) + 16384 (V)
#define V_OFF    18432

// ---------------- K_prep ----------------
__global__ __launch_bounds__(256) void k_prep(const float* __restrict__ y,
                                              const float* __restrict__ R,
                                              const float* __restrict__ t,
                                              const float* __restrict__ X,
                                              unsigned short* __restrict__ ctp) {
  __shared__ union {
    struct { unsigned short ytt[128 * 132]; float ynl[128]; } yb;
    float xt[65 * 132];
  } sm;
  const int tid = threadIdx.x;

  if (blockIdx.x < 64) {
    // ------- yt = y@R^T + t; store KA2C*yt (bf16) + yn hi/lo slots -------
    const int wv = tid >> 6, ln = tid & 63;
    const int l = ln & 31, h = ln >> 5;
    const int B = blockIdx.x;
    const int rw = B * 128 + wv * 32;

    bf16x8 af[8];  // A-frag: y[rw+l][kc*16+8h+0..7]
    {
      int row = rw + l; if (row > 8190) row = 8190;
      const float* yr = y + (size_t)row * 128;
#pragma unroll
      for (int kc = 0; kc < 8; ++kc) {
        float4 p0 = *(const float4*)(yr + kc*16 + 8*h);
        float4 p1 = *(const float4*)(yr + kc*16 + 8*h + 4);
        af[kc] = pack8(p0, p1);
      }
    }
    f32x16 acc[4];
#pragma unroll
    for (int cc=0; cc<4; ++cc)
#pragma unroll
      for (int i=0;i<16;++i) acc[cc][i] = 0.f;
#pragma unroll
    for (int cc=0; cc<4; ++cc) {
      const float* Rr = R + (size_t)(cc*32 + l) * 128;  // B-frag: R^T[k][c] = R[c][k]
#pragma unroll
      for (int kc=0; kc<8; ++kc) {
        float4 p0 = *(const float4*)(Rr + kc*16 + 8*h);
        float4 p1 = *(const float4*)(Rr + kc*16 + 8*h + 4);
        acc[cc] = mfma_32x32x16(af[kc], pack8(p0, p1), acc[cc]);
      }
    }
    // D: lane holds yt[rw + (r&3)+8*(r>>2)+4h][cc*32 + l]
    float tv0 = t[l], tv1 = t[32+l], tv2 = t[64+l], tv3 = t[96+l];
    float v0[16], v1[16], v2[16], v3[16], ssq[16];
#pragma unroll
    for (int r=0;r<16;++r) {
      v0[r]=acc[0][r]+tv0; v1[r]=acc[1][r]+tv1; v2[r]=acc[2][r]+tv2; v3[r]=acc[3][r]+tv3;
      ssq[r] = v0[r]*v0[r] + v1[r]*v1[r] + v2[r]*v2[r] + v3[r]*v3[r];
    }
#pragma unroll
    for (int off=1; off<32; off<<=1)
#pragma unroll
      for (int r=0;r<16;++r) ssq[r] += __shfl_xor(ssq[r], off, 64);
    if (l < 16) {
      int r = l;
      int rloc = wv*32 + (r&3) + 8*(r>>2) + 4*h;
      int grow = rw + (r&3) + 8*(r>>2) + 4*h;
      sm.yb.ynl[rloc] = (grow >= 8191) ? -1.0e4f : KNEG * ssq[r];  // pad j: g=0
    }
    // transpose scaled yt via LDS
#pragma unroll
    for (int r=0;r<16;++r) {
      int rloc = wv*32 + (r&3) + 8*(r>>2) + 4*h;
      sm.yb.ytt[rloc*132 +   0 + l] = f2bf(KA2C * v0[r]);
      sm.yb.ytt[rloc*132 +  32 + l] = f2bf(KA2C * v1[r]);
      sm.yb.ytt[rloc*132 +  64 + l] = f2bf(KA2C * v2[r]);
      sm.yb.ytt[rloc*132 +  96 + l] = f2bf(KA2C * v3[r]);
    }
    __syncthreads();
    // perm: [T][jc(2)][kc(9)][lane(64)][8 bf16]; lane ln -> tile-row jc*32+l, k = kc*16+8h
    const int Tt = B*2 + (wv>>1);
    const int jcw = wv & 1;
    char* base = (char*)ctp + (size_t)Tt*T_STRIDE;
#pragma unroll
    for (int kc=0;kc<8;++kc) {
      const unsigned short* s = &sm.yb.ytt[(wv*32 + l)*132 + kc*16 + 8*h];
      uint2 a = *(const uint2*)(s);
      uint2 b = *(const uint2*)(s + 4);
      uint4 o; o.x=a.x; o.y=a.y; o.z=b.x; o.w=b.y;
      *(uint4*)(base + (jcw*9 + kc)*1024 + ln*16) = o;
    }
    {  // kc=8: k=128 -> yn_hi, k=129 -> yn_lo (h=0 only)
      float yn = sm.yb.ynl[wv*32 + l];
      unsigned short hi = f2bf(yn);
      float hif = __builtin_bit_cast(float, (unsigned)hi << 16);
      unsigned short lo = f2bf(yn - hif);
      uint4 o; o.x = (h == 0) ? ((unsigned)hi | ((unsigned)lo << 16)) : 0u;
      o.y = 0u; o.z = 0u; o.w = 0u;
      *(uint4*)(base + (jcw*9 + 8)*1024 + ln*16) = o;
    }
  } else {
    // ------- V = X[1:] transposed perm -------
    const int T = blockIdx.x - 64;
    const int jt = T * 64;
    {
      int rr = tid >> 2, q4 = tid & 3;
      int row = jt + rr; if (row > 8191) row = 8191;
      const float* src = X + (size_t)row*128 + q4*32;
      float* dst = &sm.xt[rr*132 + q4*32];
#pragma unroll
      for (int i=0;i<8;++i) *(float4*)(dst + i*4) = *(const float4*)(src + i*4);
      if (tid < 4) {
        int row2 = jt + 64; if (row2 > 8191) row2 = 8191;  // clamp (pad j has g=0)
        const float* s2 = X + (size_t)row2*128 + tid*32;
        float* d2 = &sm.xt[64*132 + tid*32];
#pragma unroll
        for (int i=0;i<8;++i) *(float4*)(d2 + i*4) = *(const float4*)(s2 + i*4);
      }
    }
    __syncthreads();
    // [T][jc16(4)][cc(4)][lane(64)][8 bf16]: lane -> X1[jc16*16+8h+i][cc*32+l]
    char* base = (char*)ctp + (size_t)T*T_STRIDE + V_OFF;
#pragma unroll
    for (int it=0; it<4; ++it) {
      int E = tid + it*256;
      int lp = E & 63, grp = E >> 6;
      int cc = grp & 3, jc16 = grp >> 2;
      int jb = jc16*16 + 8*(lp>>5);
      int c  = cc*32 + (lp & 31);
      uint4 o;
      o.x = pk2bf(sm.xt[(jb+1)*132 + c], sm.xt[(jb+2)*132 + c]);
      o.y = pk2bf(sm.xt[(jb+3)*132 + c], sm.xt[(jb+4)*132 + c]);
      o.z = pk2bf(sm.xt[(jb+5)*132 + c], sm.xt[(jb+6)*132 + c]);
      o.w = pk2bf(sm.xt[(jb+7)*132 + c], sm.xt[(jb+8)*132 + c]);
      *(uint4*)(base + E*16) = o;
    }
  }
}

// ---------------- K_main ----------------
// grid (64, js); block 256 = 4 waves x 32 query rows (BM=128).
__global__ __launch_bounds__(256, 3) void k_main(
    const float* __restrict__ X,
    const unsigned short* __restrict__ ctp,
    float* __restrict__ accp,
    float* __restrict__ rsp,
    int js) {
  __shared__ unsigned short stg[T_STRIDE/2];   // 34816 B: yt(9kc x 2jc) + V
  __shared__ unsigned short gls[4*32*68];      // per-wave P scratch, stride 68 (2-way free)
  const int tid = threadIdx.x;
  const int wv = tid >> 6, ln = tid & 63;
  const int l = ln & 31, h = ln >> 5;
  const int row = blockIdx.x*128 + wv*32 + l;  // query row, always < 8192

  bf16x8 qf[9];  // Q as B-operand: x[row][k], plus k=128,129 -> 1,1 (h=0)
  {
    const float* xr = X + (size_t)row * 128;
#pragma unroll
    for (int kc=0;kc<8;++kc) {
      float4 p0 = *(const float4*)(xr + kc*16 + 8*h);
      float4 p1 = *(const float4*)(xr + kc*16 + 8*h + 4);
      qf[kc] = pack8(p0, p1);
    }
    uint4 o; o.x = (h == 0) ? 0x3F803F80u : 0u; o.y = 0u; o.z = 0u; o.w = 0u;
    qf[8] = __builtin_bit_cast(bf16x8, o);
  }
  f32x16 acc[4];
#pragma unroll
  for (int cc=0;cc<4;++cc)
#pragma unroll
    for (int i=0;i<16;++i) acc[cc][i]=0.f;
  float rs = 0.f;
  const int sp = blockIdx.y;
  const int Tbeg = (sp * 128) / js;
  const int Tend = ((sp + 1) * 128) / js;
  for (int T = Tbeg; T < Tend; ++T) {
    __syncthreads();  // previous-tile reads done before restage
    {
      const char* cb = (const char*)ctp + (size_t)T*T_STRIDE;
#pragma unroll
      for (int i=0;i<9;++i) {
        int c = wv + 4*i;
        if (c < 34) gl2lds16(cb + c*1024 + ln*16, (char*)stg + c*1024);
      }
    }
    __syncthreads();  // drains vmcnt -> staged data visible
#pragma unroll
    for (int jc=0; jc<2; ++jc) {
      f32x16 sa;
#pragma unroll
      for (int i=0;i<16;++i) sa[i]=0.f;
#pragma unroll
      for (int kc=0;kc<9;++kc) {  // e^T = (KA2C yt)·x + yn  directly
        bf16x8 a = *(const bf16x8*)((const char*)stg + (jc*9+kc)*1024 + ln*16);
        sa = mfma_32x32x16(a, qf[kc], sa);
      }
      // lane holds e[j = jc*32 + i + 8*rg + 4h][m = l] at sa[rg*4+i]
#pragma unroll
      for (int rg=0; rg<4; ++rg) {
        float g0 = fast_exp2(sa[rg*4+0]);
        float g1 = fast_exp2(sa[rg*4+1]);
        float g2 = fast_exp2(sa[rg*4+2]);
        float g3 = fast_exp2(sa[rg*4+3]);
        rs += (g0+g1) + (g2+g3);
        uint2 w; w.x = pk2bf(g0, g1); w.y = pk2bf(g2, g3);
        int j0 = jc*32 + 8*rg + 4*h;
        *(uint2*)&gls[(wv*32+l)*68 + j0] = w;   // 8B-aligned b64 write
      }
      __builtin_amdgcn_wave_barrier();
#pragma unroll
      for (int jj=0; jj<2; ++jj) {
        int jc16 = jc*2 + jj;
        const unsigned short* gp = &gls[(wv*32+l)*68 + jc16*16 + 8*h];
        uint2 g0 = *(const uint2*)(gp);
        uint2 g1 = *(const uint2*)(gp + 4);
        uint4 gv; gv.x=g0.x; gv.y=g0.y; gv.z=g1.x; gv.w=g1.y;
        bf16x8 pb = __builtin_bit_cast(bf16x8, gv);
#pragma unroll
        for (int cc=0;cc<4;++cc) {
          bf16x8 a2 = *(const bf16x8*)((const char*)stg + V_OFF + (jc16*4+cc)*1024 + ln*16);
          acc[cc] = mfma_32x32x16(a2, pb, acc[cc]);
        }
      }
      __builtin_amdgcn_wave_barrier();
    }
  }
  rs += __shfl_xor(rs, 32, 64);
  if (h == 0) rsp[(size_t)sp*8192 + row] = rs;
  // acc^T: lane holds out^T[c = cc*32+(r&3)+8(r>>2)+4h][m = row]; store [sp][c][row]
#pragma unroll
  for (int cc=0;cc<4;++cc)
#pragma unroll
    for (int r=0;r<16;++r) {
      int c = cc*32 + (r&3) + 8*(r>>2) + 4*h;
      accp[((size_t)sp*128 + c)*8192 + row] = acc[cc][r];
    }
}

// ---------------- K_fin ----------------
__global__ __launch_bounds__(256) void k_fin(const float* __restrict__ accp,
                                             const float* __restrict__ rsp,
                                             float* __restrict__ out,
                                             int js) {
  __shared__ float tr[64*132];
  __shared__ float rinv[64];
  const int tid = threadIdx.x;
  const int r0 = blockIdx.x * 64;
  if (tid < 64) {
    float s = 0.f;
    for (int sp=0; sp<js; ++sp) s += rsp[(size_t)sp*8192 + r0 + tid];
    rinv[tid] = 1.f / s;
  }
  const int rq = tid & 15, cg = tid >> 4;
  float v[8][4];
#pragma unroll
  for (int cc=0;cc<8;++cc)
#pragma unroll
    for (int k=0;k<4;++k) v[cc][k]=0.f;
  for (int sp=0; sp<js; ++sp) {
    const float* base = accp + ((size_t)sp*128 + cg*8)*8192 + r0 + rq*4;
#pragma unroll
    for (int cc=0; cc<8; ++cc) {
      float4 p = *(const float4*)(base + (size_t)cc*8192);
      v[cc][0]+=p.x; v[cc][1]+=p.y; v[cc][2]+=p.z; v[cc][3]+=p.w;
    }
  }
  __syncthreads();
#pragma unroll
  for (int cc=0;cc<8;++cc)
#pragma unroll
    for (int k=0;k<4;++k)
      tr[(rq*4+k)*132 + cg*8+cc] = v[cc][k] * rinv[rq*4+k];
  __syncthreads();
  {
    int r = tid >> 2, q = tid & 3;
    int grow = r0 + r;
    if (grow < 8191) {
      float* dst = out + (size_t)grow*128 + q*32;
      const float* s2 = &tr[r*132 + q*32];
#pragma unroll
      for (int i=0;i<8;++i) *(float4*)(dst + i*4) = *(const float4*)(s2 + i*4);
    }
  }
}

extern "C" void kernel_launch(void* const* d_in, const int* in_sizes, int n_in,
                              void* d_out, int out_size, void* d_ws, size_t ws_size,
                              hipStream_t stream) {
  const float* X = (const float*)d_in[0];
  const float* y = (const float*)d_in[1];
  // d_in[2] = y_next (unused by reference)
  const float* R = (const float*)d_in[3];
  const float* t = (const float*)d_in[4];
  float* out = (float*)d_out;
  char* ws = (char*)d_ws;

  unsigned short* ctp = (unsigned short*)ws;                 // 128 * 34816 = 4.456 MB
  size_t rspoff = (size_t)128 * T_STRIDE;
  float* rsp  = (float*)(ws + rspoff);                       // js*8192*4 <= 512 KB
  size_t accoff = rspoff + 512*1024;
  float* accp = (float*)(ws + accoff);                       // js * 4 MB

  int js = 12;  // 64 x 12 = 768 blocks = exactly 3 blocks/CU (reg-capacity limit)
  while (js > 1 && accoff + (size_t)js*128*8192*4 > ws_size) js >>= 1;

  k_prep<<<dim3(192), dim3(256), 0, stream>>>(y, R, t, X, ctp);
  k_main<<<dim3(64, js), dim3(256), 0, stream>>>(X, ctp, accp, rsp, js);
  k_fin<<<dim3(128), dim3(256), 0, stream>>>(accp, rsp, out, js);
}